// Round 14
// baseline (52.888 us; speedup 1.0000x reference)
//
#include <hip/hip_runtime.h>

#define IMGW 28
#define OUTW 26
#define FLAT (OUTW * OUTW)
#define NCLS 10
#define WROW 28   // padded col dim of wL rows (float4 reach at c0=24 hits 26,27)

// lane = TWO images (img, img+64); block = 512 threads = 8 waves handles 128
// images; grid 256 = exactly 1 block/CU. Waves 0..6 take 4-wide output-column
// strips (c0 = 0,4,...,24; wave6 masks to 2 cols; wave7 helps stage + idles).
// Key change vs round 7 (40.5us best): each wave-uniform broadcast weight
// float4 (ds_read_b128 from wL[r][c][28]) now feeds 8 FMAs (2 images) instead
// of 4 -> DS-per-FMA halved, and each ds-latency window holds 2x independent
// VALU work. Image rows load as float4+float2 (6 floats used) -> L3 read
// amplification 2x -> 1.5x. Per-class W consume keeps live W registers ~8-24
// (round 13's 80-reg wA/wB double-buffer hit the 128 cap and spilled:
// WRITE_SIZE 12.8MB). Register budget ~106 < 128 cap from (512,2)
// (min-BLOCKS semantics on this toolchain).
__global__ __launch_bounds__(512, 2) void fused_conv_fc_kernel(
    const float* __restrict__ x,       // [B, 784]
    const float* __restrict__ conv_w,  // [3,3]
    const float* __restrict__ fc_w,    // [10, 676]
    const float* __restrict__ fc_b,    // [10]
    float* __restrict__ out)           // [B, 10]
{
    __shared__ float wL[OUTW * NCLS * WROW];    // 29120 B
    __shared__ float part[6][64][2][NCLS];      // 30720 B

    const int tid  = threadIdx.x;
    const int lane = tid & 63;
    const int wid  = __builtin_amdgcn_readfirstlane(tid >> 6);
    const int imgA = blockIdx.x * 128 + lane;
    const int imgB = imgA + 64;

    const float* ipA = x + (size_t)imgA * (IMGW * IMGW);
    const float* ipB = x + (size_t)imgB * (IMGW * IMGW);

    // stage fc_w -> wL[(r*10+c)*28 + cc] = fc_w[c*676 + r*26 + cc]
    for (int i = tid; i < NCLS * FLAT; i += 512) {
        int c    = i / FLAT;
        int rest = i - c * FLAT;
        int r    = rest / OUTW;
        int cc   = rest - r * OUTW;
        wL[(r * NCLS + c) * WROW + cc] = fc_w[i];
    }
    for (int i = tid; i < OUTW * NCLS * 2; i += 512) {   // zero pad cols 26,27
        int rc = i >> 1;
        wL[rc * WROW + OUTW + (i & 1)] = 0.f;
    }

    // uniform conv weights -> SGPRs
    const float cw0 = conv_w[0], cw1 = conv_w[1], cw2 = conv_w[2];
    const float cw3 = conv_w[3], cw4 = conv_w[4], cw5 = conv_w[5];
    const float cw6 = conv_w[6], cw7 = conv_w[7], cw8 = conv_w[8];

    __syncthreads();

    float aA[NCLS], aB[NCLS];
#pragma unroll
    for (int c = 0; c < NCLS; ++c) { aA[c] = 0.f; aB[c] = 0.f; }

    if (wid < 7) {
        const int  c0   = (wid == 6) ? 24 : 4 * wid;  // 16B-aligned strip start
        const int  wv   = (wid == 6) ? 2  : 4;        // valid out cols
        const bool full = (wid != 6);                 // wave-uniform

        const float* wbase = &wL[c0];   // uniform per wave

        // rolling 4-slot row buffers, 6 floats each, both images
        __attribute__((aligned(16))) float bA0[6], bA1[6], bA2[6], bA3[6];
        __attribute__((aligned(16))) float bB0[6], bB1[6], bB2[6], bB3[6];

#define LOADR(BUFA, BUFB, RR) do {                                     \
        const float* _pa = ipA + (RR) * IMGW + c0;                     \
        const float* _pb = ipB + (RR) * IMGW + c0;                     \
        *(float4*)&BUFA[0] = *(const float4*)_pa;                      \
        *(float4*)&BUFB[0] = *(const float4*)_pb;                      \
        if (full) {                                                    \
            *(float2*)&BUFA[4] = *(const float2*)(_pa + 4);            \
            *(float2*)&BUFB[4] = *(const float2*)(_pb + 4);            \
        }                                                              \
    } while (0)

        if (!full) {   // slots 4,5 never written for wave6; keep finite
            bA0[4]=bA0[5]=bA1[4]=bA1[5]=bA2[4]=bA2[5]=bA3[4]=bA3[5]=0.f;
            bB0[4]=bB0[5]=bB1[4]=bB1[5]=bB2[4]=bB2[5]=bB3[4]=bB3[5]=0.f;
        }

        LOADR(bA0, bB0, 0); LOADR(bA1, bB1, 1);
        LOADR(bA2, bB2, 2); LOADR(bA3, bB3, 3);

        // body R: conv h for both images (VALU, covers ds latency) ||
        // image prefetch || per-class W b128 broadcast -> 8 FMAs.
#define BODY(A0, A1, A2, B0, B1, B2, LA, LB, RL, R, DO_IMG) do {       \
        float hA[4], hB[4];                                            \
        _Pragma("unroll")                                              \
        for (int j = 0; j < 4; ++j) {                                  \
            float tA = A0[j]   * cw0 + A0[j+1] * cw1 + A0[j+2] * cw2   \
                     + A1[j]   * cw3 + A1[j+1] * cw4 + A1[j+2] * cw5   \
                     + A2[j]   * cw6 + A2[j+1] * cw7 + A2[j+2] * cw8;  \
            float tB = B0[j]   * cw0 + B0[j+1] * cw1 + B0[j+2] * cw2   \
                     + B1[j]   * cw3 + B1[j+1] * cw4 + B1[j+2] * cw5   \
                     + B2[j]   * cw6 + B2[j+1] * cw7 + B2[j+2] * cw8;  \
            tA = fmaxf(tA, 0.f); tB = fmaxf(tB, 0.f);                  \
            hA[j] = (j >= wv) ? 0.f : tA;                              \
            hB[j] = (j >= wv) ? 0.f : tB;                              \
        }                                                              \
        if (DO_IMG) LOADR(LA, LB, RL);                                 \
        const float* _w = wbase + (R) * (NCLS * WROW);                 \
        _Pragma("unroll")                                              \
        for (int c = 0; c < NCLS; ++c) {                               \
            float4 wf = *(const float4*)&_w[c * WROW];                 \
            aA[c] = fmaf(hA[0], wf.x, aA[c]);                          \
            aA[c] = fmaf(hA[1], wf.y, aA[c]);                          \
            aA[c] = fmaf(hA[2], wf.z, aA[c]);                          \
            aA[c] = fmaf(hA[3], wf.w, aA[c]);                          \
            aB[c] = fmaf(hB[0], wf.x, aB[c]);                          \
            aB[c] = fmaf(hB[1], wf.y, aB[c]);                          \
            aB[c] = fmaf(hB[2], wf.z, aB[c]);                          \
            aB[c] = fmaf(hB[3], wf.w, aB[c]);                          \
        }                                                              \
    } while (0)

        int r = 0;
#pragma unroll 1
        for (int t6 = 0; t6 < 6; ++t6) {     // rows 0..23; img loads reach 27
            BODY(bA0, bA1, bA2, bB0, bB1, bB2, bA0, bB0, r + 4, r + 0, true);
            BODY(bA1, bA2, bA3, bB1, bB2, bB3, bA1, bB1, r + 5, r + 1, true);
            BODY(bA2, bA3, bA0, bB2, bB3, bB0, bA2, bB2, r + 6, r + 2, true);
            BODY(bA3, bA0, bA1, bB3, bB0, bB1, bA3, bB3, r + 7, r + 3, true);
            r += 4;
        }
        // bodies 24,25: slots hold rows 24..27; no prefetch
        BODY(bA0, bA1, bA2, bB0, bB1, bB2, bA0, bB0, 0, 24, false);
        BODY(bA1, bA2, bA3, bB1, bB2, bB3, bA1, bB1, 0, 25, false);
#undef LOADR
#undef BODY
    }

    if (wid >= 1 && wid < 7) {
#pragma unroll
        for (int c = 0; c < NCLS; ++c) {
            part[wid - 1][lane][0][c] = aA[c];
            part[wid - 1][lane][1][c] = aB[c];
        }
    }
    __syncthreads();
    if (wid == 0) {
        float vA[NCLS], vB[NCLS];
#pragma unroll
        for (int c = 0; c < NCLS; ++c) {
            float tA = aA[c], tB = aB[c];
#pragma unroll
            for (int w = 0; w < 6; ++w) {
                tA += part[w][lane][0][c];
                tB += part[w][lane][1][c];
            }
            float bb = fc_b[c];
            vA[c] = tA + bb;
            vB[c] = tB + bb;
        }
        float* oA = out + (size_t)imgA * NCLS;
        float* oB = out + (size_t)imgB * NCLS;
#pragma unroll
        for (int q = 0; q < 5; ++q) {
            *(float2*)(oA + 2 * q) = make_float2(vA[2 * q], vA[2 * q + 1]);
            *(float2*)(oB + 2 * q) = make_float2(vB[2 * q], vB[2 * q + 1]);
        }
    }
}

extern "C" void kernel_launch(void* const* d_in, const int* in_sizes, int n_in,
                              void* d_out, int out_size, void* d_ws, size_t ws_size,
                              hipStream_t stream) {
    const float* x      = (const float*)d_in[0];
    const float* conv_w = (const float*)d_in[1];
    const float* fc_w   = (const float*)d_in[2];
    const float* fc_b   = (const float*)d_in[3];
    float* out = (float*)d_out;

    const int nimg   = in_sizes[0] / (IMGW * IMGW);  // 32768
    const int blocks = nimg / 128;                   // 256 = 1 block/CU

    hipLaunchKernelGGL(fused_conv_fc_kernel, dim3(blocks), dim3(512), 0, stream,
                       x, conv_w, fc_w, fc_b, out);
}